// Round 3
// baseline (740.377 us; speedup 1.0000x reference)
//
#include <hip/hip_runtime.h>
#include <math.h>

#define BATCH 32
#define SEQ   4096
#define DM    256
#define NS    64

// z-space recurrence: z = a*z + u, x = B_tilde * z exactly.
// y = sum_n (C*B_tilde)[n] * z[n].
// chain = one (b,d) recurrence. 2 lanes per chain, 32 states per lane.
// wave = 64 lanes = 32 chains = (one b, 32 consecutive d).
// amdgpu_waves_per_eu(4,4): pin occupancy so the 96-float live set gets a
// 128-VGPR budget (round-2 regression: compiler chose 64 VGPR + scratch
// spill -> +128MB WRITE_SIZE). 4-deep u prefetch hides HBM latency.

// Pass 1: local z-scan from zero per chunk; store end z-state into S[g].
// Launched for chunks 0..C-2 only (last chunk's local state is unused).
__global__ __launch_bounds__(256) __attribute__((amdgpu_waves_per_eu(4, 4)))
void pass1_kernel(const float* __restrict__ u,
                  const float* __restrict__ log_dt,
                  const float* __restrict__ A_real,
                  float* __restrict__ S, int Tc) {
    int wave = (blockIdx.x * blockDim.x + threadIdx.x) >> 6;
    int lane = threadIdx.x & 63;
    int wc = wave & 255;   // chain group within chunk
    int g  = wave >> 8;    // chunk
    int b  = wc >> 3;
    int d0 = (wc & 7) << 5;
    int c   = lane >> 1;   // chain within wave (0..31)
    int sub = lane & 1;    // half of the state vector
    int d   = d0 + c;
    int n0  = sub << 5;

    float a[32], z[32];
    {
        float dt = expf(log_dt[d]);  // DT_SCALE = 1.0
        const float* Ap = A_real + d * NS + n0;
#pragma unroll
        for (int k = 0; k < 32; ++k) {
            a[k] = expf(Ap[k] * dt);
            z[k] = 0.0f;
        }
    }

    const float* uptr = u + (size_t)b * SEQ * DM + (size_t)(g * Tc) * DM + d;

#define P1STEP(UV)                                   \
    {                                                \
        _Pragma("unroll")                            \
        for (int k = 0; k < 32; ++k)                 \
            z[k] = fmaf(a[k], z[k], (UV));           \
    }

    float uc0 = uptr[0], uc1 = uptr[DM], uc2 = uptr[2 * DM], uc3 = uptr[3 * DM];
    for (int t4 = 0; t4 < Tc - 4; t4 += 4) {
        const float* up = uptr + 4 * DM;
        float uf0 = up[0], uf1 = up[DM], uf2 = up[2 * DM], uf3 = up[3 * DM];
        P1STEP(uc0) P1STEP(uc1) P1STEP(uc2) P1STEP(uc3)
        uc0 = uf0; uc1 = uf1; uc2 = uf2; uc3 = uf3;
        uptr = up;
    }
    P1STEP(uc0) P1STEP(uc1) P1STEP(uc2) P1STEP(uc3)
#undef P1STEP

    float* Sp = S + (((size_t)g * BATCH + b) * DM + d) * NS + n0;
    float4* Sp4 = (float4*)Sp;
#pragma unroll
    for (int j = 0; j < 8; ++j)
        Sp4[j] = make_float4(z[4 * j], z[4 * j + 1], z[4 * j + 2], z[4 * j + 3]);
}

// Pass 2: sequential chunk combine in z-space, in place. After this, S[g]
// holds the true initial z-state for chunk g (z0[0] = x0 / B_tilde, guarded).
__global__ void pass2_kernel(float* __restrict__ S,
                             const float* __restrict__ log_dt,
                             const float* __restrict__ A_real,
                             const float* __restrict__ B,
                             const float* __restrict__ x0,
                             int C, int Tc) {
    int idx = blockIdx.x * blockDim.x + threadIdx.x;  // b*16384 + d*64 + n
    if (idx >= BATCH * DM * NS) return;
    int dn = idx & (DM * NS - 1);
    int d = dn >> 6;
    float ar = A_real[dn];
    float dt = expf(log_dt[d]);
    float aT = expf(ar * dt * (float)Tc);  // a^Tc
    float x0v = x0[dn];
    float prev;
    if (x0v == 0.0f) {
        prev = 0.0f;                       // common/bench case
    } else {
        float at = expf(ar * dt);
        float bt = (1.0f - at) * B[dn] / ar;
        prev = (bt != 0.0f) ? (x0v / bt) : 0.0f;
    }
    for (int g = 0; g < C; ++g) {
        float* p = S + (size_t)g * (BATCH * DM * NS) + idx;
        float s = *p;
        *p = prev;
        prev = fmaf(aT, prev, s);   // for g == C-1, s is unused garbage (dead)
    }
}

// Pass 3: full z-scan per chunk from S[g], emit y = dot(cbt, z) every step.
__global__ __launch_bounds__(256) __attribute__((amdgpu_waves_per_eu(4, 4)))
void pass3_kernel(const float* __restrict__ u,
                  const float* __restrict__ log_dt,
                  const float* __restrict__ A_real,
                  const float* __restrict__ B,
                  const float* __restrict__ Cm,
                  const float* __restrict__ S,
                  const float* __restrict__ x0,
                  float* __restrict__ y, int Tc, int useS) {
    int wave = (blockIdx.x * blockDim.x + threadIdx.x) >> 6;
    int lane = threadIdx.x & 63;
    int wc = wave & 255;
    int g  = wave >> 8;
    int b  = wc >> 3;
    int d0 = (wc & 7) << 5;
    int c   = lane >> 1;
    int sub = lane & 1;
    int d   = d0 + c;
    int n0  = sub << 5;

    float a[32], cbt[32], z[32];
    {
        float dt = expf(log_dt[d]);
        const float* Ap = A_real + d * NS + n0;
        const float* Bp = B + d * NS + n0;
        const float* Cp = Cm + d * NS + n0;
#pragma unroll
        for (int k = 0; k < 32; ++k) {
            float ar = Ap[k];
            float at = expf(ar * dt);
            a[k] = at;
            cbt[k] = Cp[k] * ((1.0f - at) * Bp[k] / ar);  // C * B_tilde
        }
        if (useS) {
            const float4* Sp4 = (const float4*)(S +
                (((size_t)g * BATCH + b) * DM + d) * NS + n0);
#pragma unroll
            for (int j = 0; j < 8; ++j) {
                float4 v = Sp4[j];
                z[4 * j] = v.x; z[4 * j + 1] = v.y;
                z[4 * j + 2] = v.z; z[4 * j + 3] = v.w;
            }
        } else {
            const float* Xp = x0 + d * NS + n0;
#pragma unroll
            for (int k = 0; k < 32; ++k) {
                float x0v = Xp[k];
                if (x0v == 0.0f) { z[k] = 0.0f; }
                else {
                    float bt = (1.0f - a[k]) * Bp[k] / Ap[k];
                    z[k] = (bt != 0.0f) ? (x0v / bt) : 0.0f;
                }
            }
        }
    }

    const float* uptr = u + (size_t)b * SEQ * DM + (size_t)(g * Tc) * DM + d;
    float* yptr = y + (size_t)b * SEQ * DM + (size_t)(g * Tc) * DM + d;

#define P3STEP(UV)                                                            \
    {                                                                         \
        float p0 = 0.f, p1 = 0.f, p2 = 0.f, p3 = 0.f;                         \
        _Pragma("unroll")                                                     \
        for (int k = 0; k < 32; k += 4) {                                     \
            z[k]   = fmaf(a[k],   z[k],   (UV)); p0 = fmaf(cbt[k],   z[k],   p0); \
            z[k+1] = fmaf(a[k+1], z[k+1], (UV)); p1 = fmaf(cbt[k+1], z[k+1], p1); \
            z[k+2] = fmaf(a[k+2], z[k+2], (UV)); p2 = fmaf(cbt[k+2], z[k+2], p2); \
            z[k+3] = fmaf(a[k+3], z[k+3], (UV)); p3 = fmaf(cbt[k+3], z[k+3], p3); \
        }                                                                     \
        float p = (p0 + p1) + (p2 + p3);                                      \
        p += __shfl_xor(p, 1);                                                \
        if (sub == 0) *yptr = p;                                              \
        yptr += DM;                                                           \
    }

    float uc0 = uptr[0], uc1 = uptr[DM], uc2 = uptr[2 * DM], uc3 = uptr[3 * DM];
    for (int t4 = 0; t4 < Tc - 4; t4 += 4) {
        const float* up = uptr + 4 * DM;
        float uf0 = up[0], uf1 = up[DM], uf2 = up[2 * DM], uf3 = up[3 * DM];
        P3STEP(uc0) P3STEP(uc1) P3STEP(uc2) P3STEP(uc3)
        uc0 = uf0; uc1 = uf1; uc2 = uf2; uc3 = uf3;
        uptr = up;
    }
    P3STEP(uc0) P3STEP(uc1) P3STEP(uc2) P3STEP(uc3)
#undef P3STEP
}

extern "C" void kernel_launch(void* const* d_in, const int* in_sizes, int n_in,
                              void* d_out, int out_size, void* d_ws, size_t ws_size,
                              hipStream_t stream) {
    const float* u      = (const float*)d_in[0];
    const float* log_dt = (const float*)d_in[1];
    const float* A_real = (const float*)d_in[2];
    const float* B      = (const float*)d_in[3];
    const float* Cm     = (const float*)d_in[4];
    const float* x0     = (const float*)d_in[5];
    float* y = (float*)d_out;
    float* S = (float*)d_ws;

    const size_t per_chunk = (size_t)BATCH * DM * NS * sizeof(float);  // 2 MB
    int C = 16;  // 4096 waves -> exactly 4 waves/SIMD resident (pinned occ.)
    while (C > 1 && (size_t)C * per_chunk > ws_size) C >>= 1;
    if ((size_t)C * per_chunk > ws_size) C = 1;
    int Tc = SEQ / C;

    if (C > 1) {
        // chunks 0..C-2 need local end-states; 256 waves/chunk, 4 waves/block
        pass1_kernel<<<dim3((C - 1) * 64), dim3(256), 0, stream>>>(
            u, log_dt, A_real, S, Tc);
        pass2_kernel<<<dim3((BATCH * DM * NS) / 256), dim3(256), 0, stream>>>(
            S, log_dt, A_real, B, x0, C, Tc);
    }
    pass3_kernel<<<dim3(C * 64), dim3(256), 0, stream>>>(
        u, log_dt, A_real, B, Cm, S, x0, y, Tc, (C > 1) ? 1 : 0);
}

// Round 4
// 553.038 us; speedup vs baseline: 1.3387x; 1.3387x over previous
//
#include <hip/hip_runtime.h>
#include <math.h>

#define BATCH 32
#define SEQ   4096
#define DM    256
#define NS    64

// z-space recurrence: z = a*z + u, x = B_tilde * z exactly.
// y = sum_n (C*B_tilde)[n] * z[n].
// chain = one (b,d) recurrence. 2 lanes per chain, 32 states per lane.
// wave = 64 lanes = 32 chains = (one b, 32 consecutive d).
// NO launch_bounds / waves_per_eu: rounds 2-3 showed any occupancy pin makes
// the allocator clamp VGPRs (40/48/64) and spill the 96-float live set
// (+122MB scratch WRITE, VALUBusy 69->45->20%). Default budget = 256 VGPR,
// spill-averse: the a[32]+cbt[32]+z[32] set stays in registers.

// Pass 1: local z-scan from zero per chunk; store end z-state into S[g].
// Launched for chunks 0..C-2 only (last chunk's local state is unused).
__global__ void pass1_kernel(const float* __restrict__ u,
                             const float* __restrict__ log_dt,
                             const float* __restrict__ A_real,
                             float* __restrict__ S, int Tc) {
    int wave = (blockIdx.x * blockDim.x + threadIdx.x) >> 6;
    int lane = threadIdx.x & 63;
    int wc = wave & 255;   // chain group within chunk
    int g  = wave >> 8;    // chunk
    int b  = wc >> 3;
    int d0 = (wc & 7) << 5;
    int c   = lane >> 1;   // chain within wave (0..31)
    int sub = lane & 1;    // half of the state vector
    int d   = d0 + c;
    int n0  = sub << 5;

    float a[32], z[32];
    {
        float dt = expf(log_dt[d]);  // DT_SCALE = 1.0
        const float* Ap = A_real + d * NS + n0;
#pragma unroll
        for (int k = 0; k < 32; ++k) {
            a[k] = expf(Ap[k] * dt);
            z[k] = 0.0f;
        }
    }

    const float* uptr = u + (size_t)b * SEQ * DM + (size_t)(g * Tc) * DM + d;

    float ucur = *uptr;
    for (int t = 0; t < Tc - 1; ++t) {
        float unext = uptr[DM];   // 1-step prefetch
        uptr += DM;
#pragma unroll
        for (int k = 0; k < 32; ++k)
            z[k] = fmaf(a[k], z[k], ucur);
        ucur = unext;
    }
#pragma unroll
    for (int k = 0; k < 32; ++k)
        z[k] = fmaf(a[k], z[k], ucur);

    float* Sp = S + (((size_t)g * BATCH + b) * DM + d) * NS + n0;
    float4* Sp4 = (float4*)Sp;
#pragma unroll
    for (int j = 0; j < 8; ++j)
        Sp4[j] = make_float4(z[4 * j], z[4 * j + 1], z[4 * j + 2], z[4 * j + 3]);
}

// Pass 2: sequential chunk combine in z-space, in place. After this, S[g]
// holds the true initial z-state for chunk g (z0[0] = x0 / B_tilde, guarded).
__global__ void pass2_kernel(float* __restrict__ S,
                             const float* __restrict__ log_dt,
                             const float* __restrict__ A_real,
                             const float* __restrict__ B,
                             const float* __restrict__ x0,
                             int C, int Tc) {
    int idx = blockIdx.x * blockDim.x + threadIdx.x;  // b*16384 + d*64 + n
    if (idx >= BATCH * DM * NS) return;
    int dn = idx & (DM * NS - 1);
    int d = dn >> 6;
    float ar = A_real[dn];
    float dt = expf(log_dt[d]);
    float aT = expf(ar * dt * (float)Tc);  // a^Tc
    float x0v = x0[dn];
    float prev;
    if (x0v == 0.0f) {
        prev = 0.0f;                       // common/bench case
    } else {
        float at = expf(ar * dt);
        float bt = (1.0f - at) * B[dn] / ar;
        prev = (bt != 0.0f) ? (x0v / bt) : 0.0f;
    }
    for (int g = 0; g < C - 1; ++g) {
        float* p = S + (size_t)g * (BATCH * DM * NS) + idx;
        float s = *p;
        *p = prev;
        prev = fmaf(aT, prev, s);
    }
    // last chunk: only needs its initial state (no local end-state stored)
    S[(size_t)(C - 1) * (BATCH * DM * NS) + idx] = prev;
}

// Pass 3: full z-scan per chunk from S[g], emit y = dot(cbt, z) every step.
__global__ void pass3_kernel(const float* __restrict__ u,
                             const float* __restrict__ log_dt,
                             const float* __restrict__ A_real,
                             const float* __restrict__ B,
                             const float* __restrict__ Cm,
                             const float* __restrict__ S,
                             const float* __restrict__ x0,
                             float* __restrict__ y, int Tc, int useS) {
    int wave = (blockIdx.x * blockDim.x + threadIdx.x) >> 6;
    int lane = threadIdx.x & 63;
    int wc = wave & 255;
    int g  = wave >> 8;
    int b  = wc >> 3;
    int d0 = (wc & 7) << 5;
    int c   = lane >> 1;
    int sub = lane & 1;
    int d   = d0 + c;
    int n0  = sub << 5;

    float a[32], cbt[32], z[32];
    {
        float dt = expf(log_dt[d]);
        const float* Ap = A_real + d * NS + n0;
        const float* Bp = B + d * NS + n0;
        const float* Cp = Cm + d * NS + n0;
#pragma unroll
        for (int k = 0; k < 32; ++k) {
            float ar = Ap[k];
            float at = expf(ar * dt);
            a[k] = at;
            cbt[k] = Cp[k] * ((1.0f - at) * Bp[k] / ar);  // C * B_tilde
        }
        if (useS) {
            const float4* Sp4 = (const float4*)(S +
                (((size_t)g * BATCH + b) * DM + d) * NS + n0);
#pragma unroll
            for (int j = 0; j < 8; ++j) {
                float4 v = Sp4[j];
                z[4 * j] = v.x; z[4 * j + 1] = v.y;
                z[4 * j + 2] = v.z; z[4 * j + 3] = v.w;
            }
        } else {
            const float* Xp = x0 + d * NS + n0;
#pragma unroll
            for (int k = 0; k < 32; ++k) {
                float x0v = Xp[k];
                if (x0v == 0.0f) { z[k] = 0.0f; }
                else {
                    float bt = (1.0f - a[k]) * Bp[k] / Ap[k];
                    z[k] = (bt != 0.0f) ? (x0v / bt) : 0.0f;
                }
            }
        }
    }

    const float* uptr = u + (size_t)b * SEQ * DM + (size_t)(g * Tc) * DM + d;
    float* yptr = y + (size_t)b * SEQ * DM + (size_t)(g * Tc) * DM + d;

    float ucur = *uptr;
    for (int t = 0; t < Tc - 1; ++t) {
        float unext = uptr[DM];   // 1-step prefetch
        uptr += DM;
        float p0 = 0.0f, p1 = 0.0f, p2 = 0.0f, p3 = 0.0f;
#pragma unroll
        for (int k = 0; k < 32; k += 4) {
            z[k]     = fmaf(a[k],     z[k],     ucur); p0 = fmaf(cbt[k],     z[k],     p0);
            z[k + 1] = fmaf(a[k + 1], z[k + 1], ucur); p1 = fmaf(cbt[k + 1], z[k + 1], p1);
            z[k + 2] = fmaf(a[k + 2], z[k + 2], ucur); p2 = fmaf(cbt[k + 2], z[k + 2], p2);
            z[k + 3] = fmaf(a[k + 3], z[k + 3], ucur); p3 = fmaf(cbt[k + 3], z[k + 3], p3);
        }
        float p = (p0 + p1) + (p2 + p3);
        p += __shfl_xor(p, 1);        // combine the two half-state partials
        if (sub == 0) *yptr = p;      // 32 consecutive d -> full 128B line
        yptr += DM;
        ucur = unext;
    }
    {   // final step
        float p0 = 0.0f, p1 = 0.0f, p2 = 0.0f, p3 = 0.0f;
#pragma unroll
        for (int k = 0; k < 32; k += 4) {
            z[k]     = fmaf(a[k],     z[k],     ucur); p0 = fmaf(cbt[k],     z[k],     p0);
            z[k + 1] = fmaf(a[k + 1], z[k + 1], ucur); p1 = fmaf(cbt[k + 1], z[k + 1], p1);
            z[k + 2] = fmaf(a[k + 2], z[k + 2], ucur); p2 = fmaf(cbt[k + 2], z[k + 2], p2);
            z[k + 3] = fmaf(a[k + 3], z[k + 3], ucur); p3 = fmaf(cbt[k + 3], z[k + 3], p3);
        }
        float p = (p0 + p1) + (p2 + p3);
        p += __shfl_xor(p, 1);
        if (sub == 0) *yptr = p;
    }
}

extern "C" void kernel_launch(void* const* d_in, const int* in_sizes, int n_in,
                              void* d_out, int out_size, void* d_ws, size_t ws_size,
                              hipStream_t stream) {
    const float* u      = (const float*)d_in[0];
    const float* log_dt = (const float*)d_in[1];
    const float* A_real = (const float*)d_in[2];
    const float* B      = (const float*)d_in[3];
    const float* Cm     = (const float*)d_in[4];
    const float* x0     = (const float*)d_in[5];
    float* y = (float*)d_out;
    float* S = (float*)d_ws;

    const size_t per_chunk = (size_t)BATCH * DM * NS * sizeof(float);  // 2 MB
    int C = 16;  // 4096 waves in pass3
    while (C > 1 && (size_t)C * per_chunk > ws_size) C >>= 1;
    if ((size_t)C * per_chunk > ws_size) C = 1;
    int Tc = SEQ / C;

    if (C > 1) {
        // chunks 0..C-2 need local end-states; 256 waves/chunk, 4 waves/block
        pass1_kernel<<<dim3((C - 1) * 64), dim3(256), 0, stream>>>(
            u, log_dt, A_real, S, Tc);
        pass2_kernel<<<dim3((BATCH * DM * NS) / 256), dim3(256), 0, stream>>>(
            S, log_dt, A_real, B, x0, C, Tc);
    }
    pass3_kernel<<<dim3(C * 64), dim3(256), 0, stream>>>(
        u, log_dt, A_real, B, Cm, S, x0, y, Tc, (C > 1) ? 1 : 0);
}